// Round 11
// baseline (1414.755 us; speedup 1.0000x reference)
//
#include <hip/hip_runtime.h>
#include <hip/hip_fp16.h>

#define NNODES 100000
#define NEDGES 1600000
#define NGRAPH 128
#define CIN 128
#define CH 64
#define COUT 7
#define NSTACK 9

#define NB 391      // buckets of 256 nodes: ceil(100000/256)
#define CHUNK 2048  // edges per histogram/scatter block
#define NC 782      // ceil(1600000/2048)

// ---------------- merged: P1 bucket histogram (LDS only) + layer-0 GEMM ----------------
template <int K>
__global__ __launch_bounds__(256) void hist_gemm_kernel(const int* __restrict__ dst,
                                                        int* __restrict__ hist, int E,
                                                        const float* __restrict__ h,
                                                        const float* __restrict__ W,
                                                        __half* __restrict__ m, int N,
                                                        int histBlocks) {
    __shared__ float Ws[K * 64];
    __shared__ int lh[NB];
    if (blockIdx.x < (unsigned)histBlocks) {
        for (int i = threadIdx.x; i < NB; i += 256) lh[i] = 0;
        __syncthreads();
        int e0 = blockIdx.x * CHUNK;
        int e1 = min(e0 + CHUNK, E);
        for (int e = e0 + threadIdx.x; e < e1; e += 256)
            atomicAdd(&lh[dst[e] >> 8], 1);   // LDS atomic
        __syncthreads();
        for (int i = threadIdx.x; i < NB; i += 256) hist[i * NC + (int)blockIdx.x] = lh[i];
        return;
    }
    // ---- GEMM part: 8 rows/wave ----
    int gb = blockIdx.x - histBlocks;
    for (int i = threadIdx.x; i < K * 64; i += 256) Ws[i] = W[i];
    __syncthreads();
    const int ROWS = 8;
    int wid = (gb * 256 + (int)threadIdx.x) >> 6;
    int lane = threadIdx.x & 63;
    long row0 = (long)wid * ROWS;
    if (row0 >= N) return;
    const float* hr = h + row0 * K + lane;

    float hv[ROWS][K / 64];
#pragma unroll
    for (int r = 0; r < ROWS; ++r)
#pragma unroll
        for (int q = 0; q < K / 64; ++q)
            hv[r][q] = hr[(size_t)r * K + q * 64];

    float acc[ROWS];
#pragma unroll
    for (int r = 0; r < ROWS; ++r) acc[r] = 0.0f;

#pragma unroll
    for (int k = 0; k < K; ++k) {
        float wv = Ws[k * 64 + lane];
#pragma unroll
        for (int r = 0; r < ROWS; ++r) {
            unsigned hb = __builtin_amdgcn_readlane(__float_as_uint(hv[r][k >> 6]), k & 63);
            acc[r] += __uint_as_float(hb) * wv;
        }
    }

    __half* mo = m + row0 * 64 + lane;
#pragma unroll
    for (int r = 0; r < ROWS; ++r) mo[r * 64] = __float2half(acc[r]);
}

// ---------------- P2a: exclusive scan of each bucket row over NC chunks ----------------
__global__ __launch_bounds__(256) void scan_chunks_kernel(int* __restrict__ hist,
                                                          int* __restrict__ btot) {
    int b = blockIdx.x;
    int t = threadIdx.x;
    int* row = hist + b * NC;
    int v[4];
    int base = 4 * t;   // 4 elements/thread covers 1024 >= NC
#pragma unroll
    for (int u = 0; u < 4; ++u) v[u] = (base + u < NC) ? row[base + u] : 0;
    int tsum = v[0] + v[1] + v[2] + v[3];
    __shared__ int s[256];
    s[t] = tsum;
    __syncthreads();
    for (int d = 1; d < 256; d <<= 1) {
        int x = (t >= d) ? s[t - d] : 0;
        __syncthreads();
        s[t] += x;
        __syncthreads();
    }
    int run = s[t] - tsum;   // exclusive prefix of thread sums
    if (t == 255) btot[b] = s[255];
#pragma unroll
    for (int u = 0; u < 4; ++u) {
        if (base + u < NC) row[base + u] = run;
        run += v[u];
    }
}

// ---------------- P2b: exclusive scan of bucket totals -> bucket bases ----------------
__global__ void scan_buckets_kernel(const int* __restrict__ btot, int* __restrict__ bbase) {
    __shared__ int s[512];
    int t = threadIdx.x;
    int v = (t < NB) ? btot[t] : 0;
    s[t] = v;
    __syncthreads();
    for (int d = 1; d < 512; d <<= 1) {
        int x = (t >= d) ? s[t - d] : 0;
        __syncthreads();
        s[t] += x;
        __syncthreads();
    }
    if (t < NB) bbase[t] = s[t] - v;
}

// ---------------- P3: scatter edges into dst buckets (LDS ranks, no global atomics) ----
__global__ __launch_bounds__(256) void scatter_kernel(const int* __restrict__ src,
                                                      const int* __restrict__ dst,
                                                      const int* __restrict__ hist,
                                                      const int* __restrict__ bbase,
                                                      int* __restrict__ src_b,
                                                      int* __restrict__ dst_b, int E) {
    __shared__ int offs[NB];
    for (int b = threadIdx.x; b < NB; b += 256)
        offs[b] = hist[b * NC + (int)blockIdx.x] + bbase[b];
    __syncthreads();
    int e0 = blockIdx.x * CHUNK;
    int e1 = min(e0 + CHUNK, E);
    for (int e = e0 + threadIdx.x; e < e1; e += 256) {
        int d = dst[e], s = src[e];
        int pos = atomicAdd(&offs[d >> 8], 1);   // LDS atomic
        src_b[pos] = s;
        dst_b[pos] = d;
    }
}

// ---- bucket_prep: per-bucket degree count + rowptr (bbase + in-bucket scan) + dinv ----
// Replaces bucket_count + dinv + the 3-kernel global scan: rowptr[node] =
// bbase[bucket] + exclusive_scan(counts within bucket). Extra block does gcnt.
__global__ __launch_bounds__(256) void bucket_prep_kernel(const int* __restrict__ dst_b,
                                                          const int* __restrict__ bbase,
                                                          const int* __restrict__ btot,
                                                          int* __restrict__ rowptr,
                                                          float* __restrict__ dinv,
                                                          const int* __restrict__ batch,
                                                          int* __restrict__ gcnt, int N) {
    if ((int)blockIdx.x == NB) {   // per-graph node counts via binary search
        int g = threadIdx.x;
        if (g >= NGRAPH) return;
        auto lb = [&](int v) {
            int lo = 0, hi = N;
            while (lo < hi) {
                int mid = (lo + hi) >> 1;
                if (batch[mid] < v) lo = mid + 1; else hi = mid;
            }
            return lo;
        };
        gcnt[g] = lb(g + 1) - lb(g);
        return;
    }
    __shared__ int c256[256];
    __shared__ int s[256];
    int t = threadIdx.x;
    c256[t] = 0;
    __syncthreads();
    int lo = bbase[blockIdx.x], n = btot[blockIdx.x];
    for (int e = lo + t; e < lo + n; e += 256) atomicAdd(&c256[dst_b[e] & 255], 1);
    __syncthreads();
    int cnt = c256[t];
    s[t] = cnt;
    __syncthreads();
    for (int d = 1; d < 256; d <<= 1) {
        int x = (t >= d) ? s[t - d] : 0;
        __syncthreads();
        s[t] += x;
        __syncthreads();
    }
    int node = blockIdx.x * 256 + t;
    if (node < N) {
        rowptr[node] = lo + (s[t] - cnt);          // bucket base + in-bucket exclusive scan
        dinv[node] = 1.0f / sqrtf((float)(cnt + 1));  // +1 self-loop
    }
}

// ---------------- bucket_fill: final CSR (col + dn), LDS ranks ----------------
__global__ __launch_bounds__(256) void bucket_fill_kernel(const int* __restrict__ src_b,
                                                          const int* __restrict__ dst_b,
                                                          const int* __restrict__ bbase,
                                                          const int* __restrict__ btot,
                                                          const int* __restrict__ rowptr,
                                                          const float* __restrict__ dinv,
                                                          int* __restrict__ col,
                                                          __half* __restrict__ dn, int N) {
    __shared__ int f256[256];
    __shared__ int rp[256];
    int t = threadIdx.x;
    f256[t] = 0;
    int node = blockIdx.x * 256 + t;
    rp[t] = (node < N) ? rowptr[node] : 0;
    __syncthreads();
    int lo = bbase[blockIdx.x], n = btot[blockIdx.x];
    for (int e = lo + t; e < lo + n; e += 256) {
        int d = dst_b[e], sv = src_b[e];
        int li = d & 255;
        int slot = atomicAdd(&f256[li], 1);   // LDS atomic
        int idx = rp[li] + slot;
        col[idx] = sv;
        dn[idx] = __float2half(dinv[sv]);   // only consumed by agg0 (m is unscaled)
    }
}

// non-temporal fp16 row-element load (bypass L2 allocation for one-shot gathers)
__device__ __forceinline__ float h2f_nt(const __half* p) {
    unsigned short u = __builtin_nontemporal_load(reinterpret_cast<const unsigned short*>(p));
    __half_raw r;
    r.x = u;
    return __half2float(__half(r));
}

// Weighted gather (agg0): a += sum_e dn_e * m[c_e][lane].
__device__ __forceinline__ float gather_wsum(const __half* __restrict__ m,
                                             const int* __restrict__ cp,
                                             const __half* __restrict__ dp, int n,
                                             float a, int lane) {
    int e = 0;
    for (; e + 16 <= n; e += 16) {
        int c[16];
        float w[16], v[16];
#pragma unroll
        for (int u = 0; u < 16; ++u) c[u] = cp[e + u];
#pragma unroll
        for (int u = 0; u < 16; ++u) w[u] = __half2float(dp[e + u]);
#pragma unroll
        for (int u = 0; u < 16; ++u) v[u] = h2f_nt(&m[(size_t)c[u] * 64 + lane]);
#pragma unroll
        for (int u = 0; u < 16; ++u) a += w[u] * v[u];
    }
    for (; e < n; ++e)
        a += __half2float(dp[e]) * h2f_nt(&m[(size_t)cp[e] * 64 + lane]);
    return a;
}

// Unweighted gather (fused layers; rows pre-scaled by dinv): a += sum_e s[c_e][lane].
__device__ __forceinline__ float gather_sum(const __half* __restrict__ m,
                                            const int* __restrict__ cp, int n,
                                            float a, int lane) {
    int e = 0;
    for (; e + 16 <= n; e += 16) {
        int c[16];
        float v[16];
#pragma unroll
        for (int u = 0; u < 16; ++u) c[u] = cp[e + u];
#pragma unroll
        for (int u = 0; u < 16; ++u) v[u] = h2f_nt(&m[(size_t)c[u] * 64 + lane]);
#pragma unroll
        for (int u = 0; u < 16; ++u) a += v[u];
    }
    for (; e < n; ++e)
        a += h2f_nt(&m[(size_t)cp[e] * 64 + lane]);
    return a;
}

// ---------------- layer-0 aggregation: s1 = dinv_i * relu(di*a + b) ----------------
__global__ __launch_bounds__(256) void agg0_kernel(const __half* __restrict__ m,
                                                   const int* __restrict__ rowptr,
                                                   const int* __restrict__ col,
                                                   const __half* __restrict__ dn,
                                                   const float* __restrict__ dinv,
                                                   const float* __restrict__ bias,
                                                   __half* __restrict__ hout, int N, int E) {
    int wid = __builtin_amdgcn_readfirstlane((blockIdx.x * 256 + threadIdx.x) >> 6);
    int lane = threadIdx.x & 63;
    if (wid >= N) return;
    int r0 = rowptr[wid];
    int r1 = (wid + 1 < N) ? rowptr[wid + 1] : E;
    float di = dinv[wid];
    float self = di * __half2float(m[(size_t)wid * 64 + lane]);
    float a = gather_wsum(m, col + r0, dn + r0, r1 - r0, self, lane);
    float h1 = fmaxf(di * a + bias[lane], 0.0f);
    hout[(size_t)wid * 64 + lane] = __float2half(di * h1);   // pre-scaled for next layer
}

// ---------------- fused layer, 2 nodes/wave: h' = relu((A h) W + b) ----------------
// Input rows pre-scaled (s = dinv*h) -> gather is an unweighted sum, edges are 4B.
// Output written pre-scaled unless scaleOut==0 (last layer, consumed by pool).
__global__ __launch_bounds__(256) void fused_kernel(const __half* __restrict__ h,
                                                    const int* __restrict__ rowptr,
                                                    const int* __restrict__ col,
                                                    const float* __restrict__ dinv,
                                                    const float* __restrict__ W,
                                                    const float* __restrict__ bias,
                                                    __half* __restrict__ hout, int N, int E,
                                                    int scaleOut) {
    __shared__ float Ws[64 * 64];
    {
        const float4* W4 = (const float4*)W;
        float4* Ws4 = (float4*)Ws;
        for (int i = threadIdx.x; i < 64 * 16; i += 256) Ws4[i] = W4[i];
    }

    int wid = __builtin_amdgcn_readfirstlane((blockIdx.x * 256 + threadIdx.x) >> 6);
    int lane = threadIdx.x & 63;
    int nodeA = wid * 2;
    int nodeB = nodeA + 1;     // N even -> nodeB < N whenever nodeA < N
    bool act = (nodeA < N);
    float gA = 0.0f, gB = 0.0f;
    float diA = 0.0f, diB = 0.0f;

    if (act) {
        int r0A = rowptr[nodeA];
        int r0B = rowptr[nodeB];
        int r1B = (nodeB + 1 < N) ? rowptr[nodeB + 1] : E;
        diA = dinv[nodeA];
        diB = dinv[nodeB];
        float aA = __half2float(h[(size_t)nodeA * 64 + lane]);   // self = s[nodeA]
        float aB = __half2float(h[(size_t)nodeB * 64 + lane]);
        const int* cpA = col + r0A;
        const int* cpB = col + r0B;
        int nA = r0B - r0A;
        int nB = r1B - r0B;
        int eA = 0, eB = 0;
        // combined rounds: 32 gathers in flight
        while (eA + 16 <= nA && eB + 16 <= nB) {
            int cA[16], cB[16];
            float vA[16], vB[16];
#pragma unroll
            for (int u = 0; u < 16; ++u) cA[u] = cpA[eA + u];
#pragma unroll
            for (int u = 0; u < 16; ++u) cB[u] = cpB[eB + u];
#pragma unroll
            for (int u = 0; u < 16; ++u) vA[u] = h2f_nt(&h[(size_t)cA[u] * 64 + lane]);
#pragma unroll
            for (int u = 0; u < 16; ++u) vB[u] = h2f_nt(&h[(size_t)cB[u] * 64 + lane]);
#pragma unroll
            for (int u = 0; u < 16; ++u) { aA += vA[u]; aB += vB[u]; }
            eA += 16;
            eB += 16;
        }
        aA = gather_sum(h, cpA + eA, nA - eA, aA, lane);
        aB = gather_sum(h, cpB + eB, nB - eB, aB, lane);
        gA = diA * aA;
        gB = diB * aB;
    }

    __syncthreads();   // W staging visible; all waves arrive

    if (act) {
        float bv = bias[lane];
        float accA = bv, accB = bv;
#pragma unroll
        for (int k = 0; k < 64; ++k) {
            float wv = Ws[k * 64 + lane];
            unsigned ga = __builtin_amdgcn_readlane(__float_as_uint(gA), k);
            unsigned gb = __builtin_amdgcn_readlane(__float_as_uint(gB), k);
            accA += __uint_as_float(ga) * wv;
            accB += __uint_as_float(gb) * wv;
        }
        accA = fmaxf(accA, 0.0f);
        accB = fmaxf(accB, 0.0f);
        if (scaleOut) { accA *= diA; accB *= diB; }   // pre-scale for next layer's gather
        hout[(size_t)nodeA * 64 + lane] = __float2half(accA);
        hout[(size_t)nodeB * 64 + lane] = __float2half(accB);
    }
}

// ---------------- pooling: segment sum over sorted batch ids ----------------
__global__ __launch_bounds__(256) void pool_kernel(const __half* __restrict__ h,
                                                   const int* __restrict__ batch,
                                                   float* __restrict__ gpool, int N) {
    const int NPW = 32;  // nodes per wave
    int wid = (blockIdx.x * 256 + threadIdx.x) >> 6;
    int lane = threadIdx.x & 63;
    int i0 = wid * NPW;
    if (i0 >= N) return;
    int i1 = min(i0 + NPW, N);
    int curg = batch[i0];
    float acc = 0.0f;
    for (int i = i0; i < i1; ++i) {
        int g = batch[i];
        if (g != curg) {
            atomicAdd(&gpool[curg * 64 + lane], acc);
            acc = 0.0f;
            curg = g;
        }
        acc += __half2float(h[(size_t)i * 64 + lane]);
    }
    atomicAdd(&gpool[curg * 64 + lane], acc);
}

// ---------------- final: out = (gpool/count) @ Wlin + blin ----------------
__global__ void final_kernel(const float* __restrict__ gpool, const int* __restrict__ gcnt,
                             const float* __restrict__ Wlin, const float* __restrict__ blin,
                             float* __restrict__ out) {
    int t = threadIdx.x;
    if (t >= NGRAPH * COUT) return;
    int g = t / COUT, o = t - g * COUT;
    float c = (float)gcnt[g];
    if (c < 1.0f) c = 1.0f;
    float s = 0.0f;
    for (int k = 0; k < 64; ++k) s += gpool[g * 64 + k] * Wlin[k * COUT + o];
    out[t] = s / c + blin[o];
}

extern "C" void kernel_launch(void* const* d_in, const int* in_sizes, int n_in,
                              void* d_out, int out_size, void* d_ws, size_t ws_size,
                              hipStream_t stream) {
    const float* x    = (const float*)d_in[0];
    const int*   ei   = (const int*)d_in[1];
    const int*   batch= (const int*)d_in[2];
    const float* W0   = (const float*)d_in[3];
    const float* b0   = (const float*)d_in[4];
    const float* Ws   = (const float*)d_in[5];
    const float* bs   = (const float*)d_in[6];
    const float* Wlin = (const float*)d_in[7];
    const float* blin = (const float*)d_in[8];
    float* out = (float*)d_out;

    const int N = NNODES, E = NEDGES;
    const int* srcp = ei;          // edge_index[0]
    const int* dstp = ei + E;      // edge_index[1]

    char* w = (char*)d_ws;
    float* gpool  = (float*)w; w += (size_t)NGRAPH * 64 * 4;
    size_t zero_bytes = (size_t)(w - (char*)d_ws);   // only gpool needs zeroing
    int*   gcnt   = (int*)w;   w += (size_t)NGRAPH * 4;
    float* dinv   = (float*)w; w += (size_t)N * 4;
    int*   rowptr = (int*)w;   w += (size_t)N * 4;
    int*   hist   = (int*)w;   w += (size_t)NB * NC * 4;
    int*   btot   = (int*)w;   w += (size_t)NB * 4;
    int*   bbase  = (int*)w;   w += (size_t)NB * 4;
    int*   src_b  = (int*)w;   w += (size_t)E * 4;
    int*   dst_b  = (int*)w;   w += (size_t)E * 4;
    int*   col    = (int*)w;   w += (size_t)E * 4;
    __half* dn    = (__half*)w; w += (size_t)E * 2;
    __half* bufA  = (__half*)w; w += (size_t)N * 64 * 2;
    __half* bufB  = (__half*)w; w += (size_t)N * 64 * 2;

    hipMemsetAsync(d_ws, 0, zero_bytes, stream);

    int gemmblocks = (N + 31) / 32;       // 3125: 8 rows/wave, 4 waves/block

    // P1 histogram + layer-0 GEMM co-scheduled (independent)
    hist_gemm_kernel<128><<<NC + gemmblocks, 256, 0, stream>>>(
        dstp, hist, E, x, W0, bufB, N, NC);
    scan_chunks_kernel<<<NB, 256, 0, stream>>>(hist, btot);
    scan_buckets_kernel<<<1, 512, 0, stream>>>(btot, bbase);
    scatter_kernel<<<NC, 256, 0, stream>>>(srcp, dstp, hist, bbase, src_b, dst_b, E);
    bucket_prep_kernel<<<NB + 1, 256, 0, stream>>>(dst_b, bbase, btot, rowptr, dinv,
                                                   batch, gcnt, N);
    bucket_fill_kernel<<<NB, 256, 0, stream>>>(src_b, dst_b, bbase, btot, rowptr, dinv,
                                               col, dn, N);

    int aggblocks = (N + 3) / 4;              // wave per node (agg0)
    int fusedblocks = ((N + 1) / 2 + 3) / 4;  // 2 nodes per wave

    agg0_kernel<<<aggblocks, 256, 0, stream>>>(bufB, rowptr, col, dn, dinv, b0, bufA, N, E);

    // layers 1..9 fused: h' = relu((A h) W + b); rows pre-scaled except the last
    __half* hin = bufA;
    __half* hout = bufB;
    for (int l = 0; l < NSTACK; ++l) {
        int scaleOut = (l < NSTACK - 1) ? 1 : 0;
        fused_kernel<<<fusedblocks, 256, 0, stream>>>(hin, rowptr, col, dinv,
                                                      Ws + (size_t)l * 64 * 64,
                                                      bs + (size_t)l * 64, hout, N, E,
                                                      scaleOut);
        __half* t = hin; hin = hout; hout = t;
    }
    // final h is in `hin` after the swap

    int pwaves = (N + 31) / 32;
    int pblocks = (pwaves + 3) / 4;
    pool_kernel<<<pblocks, 256, 0, stream>>>(hin, batch, gpool, N);
    final_kernel<<<1, 896, 0, stream>>>(gpool, gcnt, Wlin, blin, out);
}

// Round 12
// 1029.592 us; speedup vs baseline: 1.3741x; 1.3741x over previous
//
#include <hip/hip_runtime.h>
#include <hip/hip_fp16.h>

#define NNODES 100000
#define NEDGES 1600000
#define NGRAPH 128
#define CIN 128
#define CH 64
#define COUT 7
#define NSTACK 9

#define NB 391      // buckets of 256 nodes: ceil(100000/256)
#define CHUNK 2048  // edges per histogram/scatter block
#define NC 782      // ceil(1600000/2048)

// ---------------- merged: P1 bucket histogram (LDS only) + layer-0 GEMM ----------------
template <int K>
__global__ __launch_bounds__(256) void hist_gemm_kernel(const int* __restrict__ dst,
                                                        int* __restrict__ hist, int E,
                                                        const float* __restrict__ h,
                                                        const float* __restrict__ W,
                                                        __half* __restrict__ m, int N,
                                                        int histBlocks) {
    __shared__ float Ws[K * 64];
    __shared__ int lh[NB];
    if (blockIdx.x < (unsigned)histBlocks) {
        for (int i = threadIdx.x; i < NB; i += 256) lh[i] = 0;
        __syncthreads();
        int e0 = blockIdx.x * CHUNK;
        int e1 = min(e0 + CHUNK, E);
        for (int e = e0 + threadIdx.x; e < e1; e += 256)
            atomicAdd(&lh[dst[e] >> 8], 1);   // LDS atomic
        __syncthreads();
        for (int i = threadIdx.x; i < NB; i += 256) hist[i * NC + (int)blockIdx.x] = lh[i];
        return;
    }
    // ---- GEMM part: 8 rows/wave ----
    int gb = blockIdx.x - histBlocks;
    for (int i = threadIdx.x; i < K * 64; i += 256) Ws[i] = W[i];
    __syncthreads();
    const int ROWS = 8;
    int wid = (gb * 256 + (int)threadIdx.x) >> 6;
    int lane = threadIdx.x & 63;
    long row0 = (long)wid * ROWS;
    if (row0 >= N) return;
    const float* hr = h + row0 * K + lane;

    float hv[ROWS][K / 64];
#pragma unroll
    for (int r = 0; r < ROWS; ++r)
#pragma unroll
        for (int q = 0; q < K / 64; ++q)
            hv[r][q] = hr[(size_t)r * K + q * 64];

    float acc[ROWS];
#pragma unroll
    for (int r = 0; r < ROWS; ++r) acc[r] = 0.0f;

#pragma unroll
    for (int k = 0; k < K; ++k) {
        float wv = Ws[k * 64 + lane];
#pragma unroll
        for (int r = 0; r < ROWS; ++r) {
            unsigned hb = __builtin_amdgcn_readlane(__float_as_uint(hv[r][k >> 6]), k & 63);
            acc[r] += __uint_as_float(hb) * wv;
        }
    }

    __half* mo = m + row0 * 64 + lane;
#pragma unroll
    for (int r = 0; r < ROWS; ++r) mo[r * 64] = __float2half(acc[r]);
}

// ---------------- P2a: exclusive scan of each bucket row over NC chunks ----------------
__global__ __launch_bounds__(256) void scan_chunks_kernel(int* __restrict__ hist,
                                                          int* __restrict__ btot) {
    int b = blockIdx.x;
    int t = threadIdx.x;
    int* row = hist + b * NC;
    int v[4];
    int base = 4 * t;   // 4 elements/thread covers 1024 >= NC
#pragma unroll
    for (int u = 0; u < 4; ++u) v[u] = (base + u < NC) ? row[base + u] : 0;
    int tsum = v[0] + v[1] + v[2] + v[3];
    __shared__ int s[256];
    s[t] = tsum;
    __syncthreads();
    for (int d = 1; d < 256; d <<= 1) {
        int x = (t >= d) ? s[t - d] : 0;
        __syncthreads();
        s[t] += x;
        __syncthreads();
    }
    int run = s[t] - tsum;   // exclusive prefix of thread sums
    if (t == 255) btot[b] = s[255];
#pragma unroll
    for (int u = 0; u < 4; ++u) {
        if (base + u < NC) row[base + u] = run;
        run += v[u];
    }
}

// ---------------- P2b: exclusive scan of bucket totals -> bucket bases ----------------
__global__ void scan_buckets_kernel(const int* __restrict__ btot, int* __restrict__ bbase) {
    __shared__ int s[512];
    int t = threadIdx.x;
    int v = (t < NB) ? btot[t] : 0;
    s[t] = v;
    __syncthreads();
    for (int d = 1; d < 512; d <<= 1) {
        int x = (t >= d) ? s[t - d] : 0;
        __syncthreads();
        s[t] += x;
        __syncthreads();
    }
    if (t < NB) bbase[t] = s[t] - v;
}

// ---------------- P3: scatter edges into dst buckets (LDS ranks, no global atomics) ----
__global__ __launch_bounds__(256) void scatter_kernel(const int* __restrict__ src,
                                                      const int* __restrict__ dst,
                                                      const int* __restrict__ hist,
                                                      const int* __restrict__ bbase,
                                                      int* __restrict__ src_b,
                                                      int* __restrict__ dst_b, int E) {
    __shared__ int offs[NB];
    for (int b = threadIdx.x; b < NB; b += 256)
        offs[b] = hist[b * NC + (int)blockIdx.x] + bbase[b];
    __syncthreads();
    int e0 = blockIdx.x * CHUNK;
    int e1 = min(e0 + CHUNK, E);
    for (int e = e0 + threadIdx.x; e < e1; e += 256) {
        int d = dst[e], s = src[e];
        int pos = atomicAdd(&offs[d >> 8], 1);   // LDS atomic
        src_b[pos] = s;
        dst_b[pos] = d;
    }
}

// ---- bucket_prep: per-bucket degree count + rowptr (bbase + in-bucket scan) + dinv ----
__global__ __launch_bounds__(256) void bucket_prep_kernel(const int* __restrict__ dst_b,
                                                          const int* __restrict__ bbase,
                                                          const int* __restrict__ btot,
                                                          int* __restrict__ rowptr,
                                                          float* __restrict__ dinv,
                                                          const int* __restrict__ batch,
                                                          int* __restrict__ gcnt, int N) {
    if ((int)blockIdx.x == NB) {   // per-graph node counts via binary search
        int g = threadIdx.x;
        if (g >= NGRAPH) return;
        auto lb = [&](int v) {
            int lo = 0, hi = N;
            while (lo < hi) {
                int mid = (lo + hi) >> 1;
                if (batch[mid] < v) lo = mid + 1; else hi = mid;
            }
            return lo;
        };
        gcnt[g] = lb(g + 1) - lb(g);
        return;
    }
    __shared__ int c256[256];
    __shared__ int s[256];
    int t = threadIdx.x;
    c256[t] = 0;
    __syncthreads();
    int lo = bbase[blockIdx.x], n = btot[blockIdx.x];
    for (int e = lo + t; e < lo + n; e += 256) atomicAdd(&c256[dst_b[e] & 255], 1);
    __syncthreads();
    int cnt = c256[t];
    s[t] = cnt;
    __syncthreads();
    for (int d = 1; d < 256; d <<= 1) {
        int x = (t >= d) ? s[t - d] : 0;
        __syncthreads();
        s[t] += x;
        __syncthreads();
    }
    int node = blockIdx.x * 256 + t;
    if (node < N) {
        rowptr[node] = lo + (s[t] - cnt);          // bucket base + in-bucket exclusive scan
        dinv[node] = 1.0f / sqrtf((float)(cnt + 1));  // +1 self-loop
    }
}

// ---------------- bucket_fill: final CSR (col + dn), LDS ranks ----------------
__global__ __launch_bounds__(256) void bucket_fill_kernel(const int* __restrict__ src_b,
                                                          const int* __restrict__ dst_b,
                                                          const int* __restrict__ bbase,
                                                          const int* __restrict__ btot,
                                                          const int* __restrict__ rowptr,
                                                          const float* __restrict__ dinv,
                                                          int* __restrict__ col,
                                                          __half* __restrict__ dn, int N) {
    __shared__ int f256[256];
    __shared__ int rp[256];
    int t = threadIdx.x;
    f256[t] = 0;
    int node = blockIdx.x * 256 + t;
    rp[t] = (node < N) ? rowptr[node] : 0;
    __syncthreads();
    int lo = bbase[blockIdx.x], n = btot[blockIdx.x];
    for (int e = lo + t; e < lo + n; e += 256) {
        int d = dst_b[e], sv = src_b[e];
        int li = d & 255;
        int slot = atomicAdd(&f256[li], 1);   // LDS atomic
        int idx = rp[li] + slot;
        col[idx] = sv;
        dn[idx] = __float2half(dinv[sv]);   // only consumed by agg0 (m is unscaled)
    }
}

// Weighted gather (agg0): a += sum_e dn_e * m[c_e][lane].
__device__ __forceinline__ float gather_wsum(const __half* __restrict__ m,
                                             const int* __restrict__ cp,
                                             const __half* __restrict__ dp, int n,
                                             float a, int lane) {
    int e = 0;
    for (; e + 16 <= n; e += 16) {
        int c[16];
        float w[16], v[16];
#pragma unroll
        for (int u = 0; u < 16; ++u) c[u] = cp[e + u];
#pragma unroll
        for (int u = 0; u < 16; ++u) w[u] = __half2float(dp[e + u]);
#pragma unroll
        for (int u = 0; u < 16; ++u) v[u] = __half2float(m[(size_t)c[u] * 64 + lane]);
#pragma unroll
        for (int u = 0; u < 16; ++u) a += w[u] * v[u];
    }
    for (; e < n; ++e)
        a += __half2float(dp[e]) * __half2float(m[(size_t)cp[e] * 64 + lane]);
    return a;
}

// Unweighted gather (fused layers; rows pre-scaled by dinv): a += sum_e s[c_e][lane].
__device__ __forceinline__ float gather_sum(const __half* __restrict__ m,
                                            const int* __restrict__ cp, int n,
                                            float a, int lane) {
    int e = 0;
    for (; e + 16 <= n; e += 16) {
        int c[16];
        float v[16];
#pragma unroll
        for (int u = 0; u < 16; ++u) c[u] = cp[e + u];
#pragma unroll
        for (int u = 0; u < 16; ++u) v[u] = __half2float(m[(size_t)c[u] * 64 + lane]);
#pragma unroll
        for (int u = 0; u < 16; ++u) a += v[u];
    }
    for (; e < n; ++e)
        a += __half2float(m[(size_t)cp[e] * 64 + lane]);
    return a;
}

// ---------------- layer-0 aggregation: s1 = dinv_i * relu(di*a + b) ----------------
__global__ __launch_bounds__(256) void agg0_kernel(const __half* __restrict__ m,
                                                   const int* __restrict__ rowptr,
                                                   const int* __restrict__ col,
                                                   const __half* __restrict__ dn,
                                                   const float* __restrict__ dinv,
                                                   const float* __restrict__ bias,
                                                   __half* __restrict__ hout, int N, int E) {
    int wid = __builtin_amdgcn_readfirstlane((blockIdx.x * 256 + threadIdx.x) >> 6);
    int lane = threadIdx.x & 63;
    if (wid >= N) return;
    int r0 = rowptr[wid];
    int r1 = (wid + 1 < N) ? rowptr[wid + 1] : E;
    float di = dinv[wid];
    float self = di * __half2float(m[(size_t)wid * 64 + lane]);
    float a = gather_wsum(m, col + r0, dn + r0, r1 - r0, self, lane);
    float h1 = fmaxf(di * a + bias[lane], 0.0f);
    hout[(size_t)wid * 64 + lane] = __float2half(di * h1);   // pre-scaled for next layer
}

// ---------------- fused layer, 2 nodes/wave: h' = relu((A h) W + b) ----------------
// Input rows pre-scaled (s = dinv*h) -> gather is an unweighted sum, edges are 4B.
__global__ __launch_bounds__(256) void fused_kernel(const __half* __restrict__ h,
                                                    const int* __restrict__ rowptr,
                                                    const int* __restrict__ col,
                                                    const float* __restrict__ dinv,
                                                    const float* __restrict__ W,
                                                    const float* __restrict__ bias,
                                                    __half* __restrict__ hout, int N, int E,
                                                    int scaleOut) {
    __shared__ float Ws[64 * 64];
    {
        const float4* W4 = (const float4*)W;
        float4* Ws4 = (float4*)Ws;
        for (int i = threadIdx.x; i < 64 * 16; i += 256) Ws4[i] = W4[i];
    }

    int wid = __builtin_amdgcn_readfirstlane((blockIdx.x * 256 + threadIdx.x) >> 6);
    int lane = threadIdx.x & 63;
    int nodeA = wid * 2;
    int nodeB = nodeA + 1;     // N even -> nodeB < N whenever nodeA < N
    bool act = (nodeA < N);
    float gA = 0.0f, gB = 0.0f;
    float diA = 0.0f, diB = 0.0f;

    if (act) {
        int r0A = rowptr[nodeA];
        int r0B = rowptr[nodeB];
        int r1B = (nodeB + 1 < N) ? rowptr[nodeB + 1] : E;
        diA = dinv[nodeA];
        diB = dinv[nodeB];
        float aA = __half2float(h[(size_t)nodeA * 64 + lane]);   // self = s[nodeA]
        float aB = __half2float(h[(size_t)nodeB * 64 + lane]);
        const int* cpA = col + r0A;
        const int* cpB = col + r0B;
        int nA = r0B - r0A;
        int nB = r1B - r0B;
        int eA = 0, eB = 0;
        // combined rounds: 32 gathers in flight
        while (eA + 16 <= nA && eB + 16 <= nB) {
            int cA[16], cB[16];
            float vA[16], vB[16];
#pragma unroll
            for (int u = 0; u < 16; ++u) cA[u] = cpA[eA + u];
#pragma unroll
            for (int u = 0; u < 16; ++u) cB[u] = cpB[eB + u];
#pragma unroll
            for (int u = 0; u < 16; ++u) vA[u] = __half2float(h[(size_t)cA[u] * 64 + lane]);
#pragma unroll
            for (int u = 0; u < 16; ++u) vB[u] = __half2float(h[(size_t)cB[u] * 64 + lane]);
#pragma unroll
            for (int u = 0; u < 16; ++u) { aA += vA[u]; aB += vB[u]; }
            eA += 16;
            eB += 16;
        }
        aA = gather_sum(h, cpA + eA, nA - eA, aA, lane);
        aB = gather_sum(h, cpB + eB, nB - eB, aB, lane);
        gA = diA * aA;
        gB = diB * aB;
    }

    __syncthreads();   // W staging visible; all waves arrive

    if (act) {
        float bv = bias[lane];
        float accA = bv, accB = bv;
#pragma unroll
        for (int k = 0; k < 64; ++k) {
            float wv = Ws[k * 64 + lane];
            unsigned ga = __builtin_amdgcn_readlane(__float_as_uint(gA), k);
            unsigned gb = __builtin_amdgcn_readlane(__float_as_uint(gB), k);
            accA += __uint_as_float(ga) * wv;
            accB += __uint_as_float(gb) * wv;
        }
        accA = fmaxf(accA, 0.0f);
        accB = fmaxf(accB, 0.0f);
        if (scaleOut) { accA *= diA; accB *= diB; }   // pre-scale for next layer's gather
        hout[(size_t)nodeA * 64 + lane] = __float2half(accA);
        hout[(size_t)nodeB * 64 + lane] = __float2half(accB);
    }
}

// ---------------- pooling: segment sum over sorted batch ids ----------------
__global__ __launch_bounds__(256) void pool_kernel(const __half* __restrict__ h,
                                                   const int* __restrict__ batch,
                                                   float* __restrict__ gpool, int N) {
    const int NPW = 32;  // nodes per wave
    int wid = (blockIdx.x * 256 + threadIdx.x) >> 6;
    int lane = threadIdx.x & 63;
    int i0 = wid * NPW;
    if (i0 >= N) return;
    int i1 = min(i0 + NPW, N);
    int curg = batch[i0];
    float acc = 0.0f;
    for (int i = i0; i < i1; ++i) {
        int g = batch[i];
        if (g != curg) {
            atomicAdd(&gpool[curg * 64 + lane], acc);
            acc = 0.0f;
            curg = g;
        }
        acc += __half2float(h[(size_t)i * 64 + lane]);
    }
    atomicAdd(&gpool[curg * 64 + lane], acc);
}

// ---------------- final: out = (gpool/count) @ Wlin + blin ----------------
__global__ void final_kernel(const float* __restrict__ gpool, const int* __restrict__ gcnt,
                             const float* __restrict__ Wlin, const float* __restrict__ blin,
                             float* __restrict__ out) {
    int t = threadIdx.x;
    if (t >= NGRAPH * COUT) return;
    int g = t / COUT, o = t - g * COUT;
    float c = (float)gcnt[g];
    if (c < 1.0f) c = 1.0f;
    float s = 0.0f;
    for (int k = 0; k < 64; ++k) s += gpool[g * 64 + k] * Wlin[k * COUT + o];
    out[t] = s / c + blin[o];
}

extern "C" void kernel_launch(void* const* d_in, const int* in_sizes, int n_in,
                              void* d_out, int out_size, void* d_ws, size_t ws_size,
                              hipStream_t stream) {
    const float* x    = (const float*)d_in[0];
    const int*   ei   = (const int*)d_in[1];
    const int*   batch= (const int*)d_in[2];
    const float* W0   = (const float*)d_in[3];
    const float* b0   = (const float*)d_in[4];
    const float* Ws   = (const float*)d_in[5];
    const float* bs   = (const float*)d_in[6];
    const float* Wlin = (const float*)d_in[7];
    const float* blin = (const float*)d_in[8];
    float* out = (float*)d_out;

    const int N = NNODES, E = NEDGES;
    const int* srcp = ei;          // edge_index[0]
    const int* dstp = ei + E;      // edge_index[1]

    char* w = (char*)d_ws;
    float* gpool  = (float*)w; w += (size_t)NGRAPH * 64 * 4;
    size_t zero_bytes = (size_t)(w - (char*)d_ws);   // only gpool needs zeroing
    int*   gcnt   = (int*)w;   w += (size_t)NGRAPH * 4;
    float* dinv   = (float*)w; w += (size_t)N * 4;
    int*   rowptr = (int*)w;   w += (size_t)N * 4;
    int*   hist   = (int*)w;   w += (size_t)NB * NC * 4;
    int*   btot   = (int*)w;   w += (size_t)NB * 4;
    int*   bbase  = (int*)w;   w += (size_t)NB * 4;
    int*   src_b  = (int*)w;   w += (size_t)E * 4;
    int*   dst_b  = (int*)w;   w += (size_t)E * 4;
    int*   col    = (int*)w;   w += (size_t)E * 4;
    __half* dn    = (__half*)w; w += (size_t)E * 2;
    __half* bufA  = (__half*)w; w += (size_t)N * 64 * 2;
    __half* bufB  = (__half*)w; w += (size_t)N * 64 * 2;

    hipMemsetAsync(d_ws, 0, zero_bytes, stream);

    int gemmblocks = (N + 31) / 32;       // 3125: 8 rows/wave, 4 waves/block

    // P1 histogram + layer-0 GEMM co-scheduled (independent)
    hist_gemm_kernel<128><<<NC + gemmblocks, 256, 0, stream>>>(
        dstp, hist, E, x, W0, bufB, N, NC);
    scan_chunks_kernel<<<NB, 256, 0, stream>>>(hist, btot);
    scan_buckets_kernel<<<1, 512, 0, stream>>>(btot, bbase);
    scatter_kernel<<<NC, 256, 0, stream>>>(srcp, dstp, hist, bbase, src_b, dst_b, E);
    bucket_prep_kernel<<<NB + 1, 256, 0, stream>>>(dst_b, bbase, btot, rowptr, dinv,
                                                   batch, gcnt, N);
    bucket_fill_kernel<<<NB, 256, 0, stream>>>(src_b, dst_b, bbase, btot, rowptr, dinv,
                                               col, dn, N);

    int aggblocks = (N + 3) / 4;              // wave per node (agg0)
    int fusedblocks = ((N + 1) / 2 + 3) / 4;  // 2 nodes per wave

    agg0_kernel<<<aggblocks, 256, 0, stream>>>(bufB, rowptr, col, dn, dinv, b0, bufA, N, E);

    // layers 1..9 fused: h' = relu((A h) W + b); rows pre-scaled except the last
    __half* hin = bufA;
    __half* hout = bufB;
    for (int l = 0; l < NSTACK; ++l) {
        int scaleOut = (l < NSTACK - 1) ? 1 : 0;
        fused_kernel<<<fusedblocks, 256, 0, stream>>>(hin, rowptr, col, dinv,
                                                      Ws + (size_t)l * 64 * 64,
                                                      bs + (size_t)l * 64, hout, N, E,
                                                      scaleOut);
        __half* t = hin; hin = hout; hout = t;
    }
    // final h is in `hin` after the swap

    int pwaves = (N + 31) / 32;
    int pblocks = (pwaves + 3) / 4;
    pool_kernel<<<pblocks, 256, 0, stream>>>(hin, batch, gpool, N);
    final_kernel<<<1, 896, 0, stream>>>(gpool, gcnt, Wlin, blin, out);
}

// Round 13
// 999.490 us; speedup vs baseline: 1.4155x; 1.0301x over previous
//
#include <hip/hip_runtime.h>
#include <hip/hip_fp16.h>

#define NNODES 100000
#define NEDGES 1600000
#define NGRAPH 128
#define CIN 128
#define CH 64
#define COUT 7
#define NSTACK 9

#define NB 391      // buckets of 256 nodes: ceil(100000/256)
#define CHUNK 2048  // edges per histogram/scatter block
#define NC 782      // ceil(1600000/2048)

// ---------------- merged: P1 bucket histogram (LDS only) + layer-0 GEMM ----------------
template <int K>
__global__ __launch_bounds__(256) void hist_gemm_kernel(const int* __restrict__ dst,
                                                        int* __restrict__ hist, int E,
                                                        const float* __restrict__ h,
                                                        const float* __restrict__ W,
                                                        __half* __restrict__ m, int N,
                                                        int histBlocks) {
    __shared__ float Ws[K * 64];
    __shared__ int lh[NB];
    if (blockIdx.x < (unsigned)histBlocks) {
        for (int i = threadIdx.x; i < NB; i += 256) lh[i] = 0;
        __syncthreads();
        int e0 = blockIdx.x * CHUNK;
        int e1 = min(e0 + CHUNK, E);
        for (int e = e0 + threadIdx.x; e < e1; e += 256)
            atomicAdd(&lh[dst[e] >> 8], 1);   // LDS atomic
        __syncthreads();
        for (int i = threadIdx.x; i < NB; i += 256) hist[i * NC + (int)blockIdx.x] = lh[i];
        return;
    }
    // ---- GEMM part: 8 rows/wave ----
    int gb = blockIdx.x - histBlocks;
    for (int i = threadIdx.x; i < K * 64; i += 256) Ws[i] = W[i];
    __syncthreads();
    const int ROWS = 8;
    int wid = (gb * 256 + (int)threadIdx.x) >> 6;
    int lane = threadIdx.x & 63;
    long row0 = (long)wid * ROWS;
    if (row0 >= N) return;
    const float* hr = h + row0 * K + lane;

    float hv[ROWS][K / 64];
#pragma unroll
    for (int r = 0; r < ROWS; ++r)
#pragma unroll
        for (int q = 0; q < K / 64; ++q)
            hv[r][q] = hr[(size_t)r * K + q * 64];

    float acc[ROWS];
#pragma unroll
    for (int r = 0; r < ROWS; ++r) acc[r] = 0.0f;

#pragma unroll
    for (int k = 0; k < K; ++k) {
        float wv = Ws[k * 64 + lane];
#pragma unroll
        for (int r = 0; r < ROWS; ++r) {
            unsigned hb = __builtin_amdgcn_readlane(__float_as_uint(hv[r][k >> 6]), k & 63);
            acc[r] += __uint_as_float(hb) * wv;
        }
    }

    __half* mo = m + row0 * 64 + lane;
#pragma unroll
    for (int r = 0; r < ROWS; ++r) mo[r * 64] = __float2half(acc[r]);
}

// ---------------- P2a: exclusive scan of each bucket row over NC chunks ----------------
__global__ __launch_bounds__(256) void scan_chunks_kernel(int* __restrict__ hist,
                                                          int* __restrict__ btot) {
    int b = blockIdx.x;
    int t = threadIdx.x;
    int* row = hist + b * NC;
    int v[4];
    int base = 4 * t;   // 4 elements/thread covers 1024 >= NC
#pragma unroll
    for (int u = 0; u < 4; ++u) v[u] = (base + u < NC) ? row[base + u] : 0;
    int tsum = v[0] + v[1] + v[2] + v[3];
    __shared__ int s[256];
    s[t] = tsum;
    __syncthreads();
    for (int d = 1; d < 256; d <<= 1) {
        int x = (t >= d) ? s[t - d] : 0;
        __syncthreads();
        s[t] += x;
        __syncthreads();
    }
    int run = s[t] - tsum;   // exclusive prefix of thread sums
    if (t == 255) btot[b] = s[255];
#pragma unroll
    for (int u = 0; u < 4; ++u) {
        if (base + u < NC) row[base + u] = run;
        run += v[u];
    }
}

// ---------------- P2b: exclusive scan of bucket totals -> bucket bases ----------------
__global__ void scan_buckets_kernel(const int* __restrict__ btot, int* __restrict__ bbase) {
    __shared__ int s[512];
    int t = threadIdx.x;
    int v = (t < NB) ? btot[t] : 0;
    s[t] = v;
    __syncthreads();
    for (int d = 1; d < 512; d <<= 1) {
        int x = (t >= d) ? s[t - d] : 0;
        __syncthreads();
        s[t] += x;
        __syncthreads();
    }
    if (t < NB) bbase[t] = s[t] - v;
}

// ---------------- P3: scatter edges into dst buckets (LDS ranks, no global atomics) ----
__global__ __launch_bounds__(256) void scatter_kernel(const int* __restrict__ src,
                                                      const int* __restrict__ dst,
                                                      const int* __restrict__ hist,
                                                      const int* __restrict__ bbase,
                                                      int* __restrict__ src_b,
                                                      int* __restrict__ dst_b, int E) {
    __shared__ int offs[NB];
    for (int b = threadIdx.x; b < NB; b += 256)
        offs[b] = hist[b * NC + (int)blockIdx.x] + bbase[b];
    __syncthreads();
    int e0 = blockIdx.x * CHUNK;
    int e1 = min(e0 + CHUNK, E);
    for (int e = e0 + threadIdx.x; e < e1; e += 256) {
        int d = dst[e], s = src[e];
        int pos = atomicAdd(&offs[d >> 8], 1);   // LDS atomic
        src_b[pos] = s;
        dst_b[pos] = d;
    }
}

// ---- bucket_prep: per-bucket degree count + rowptr (bbase + in-bucket scan) + dinv ----
__global__ __launch_bounds__(256) void bucket_prep_kernel(const int* __restrict__ dst_b,
                                                          const int* __restrict__ bbase,
                                                          const int* __restrict__ btot,
                                                          int* __restrict__ rowptr,
                                                          float* __restrict__ dinv,
                                                          const int* __restrict__ batch,
                                                          int* __restrict__ gcnt, int N) {
    if ((int)blockIdx.x == NB) {   // per-graph node counts via binary search
        int g = threadIdx.x;
        if (g >= NGRAPH) return;
        auto lb = [&](int v) {
            int lo = 0, hi = N;
            while (lo < hi) {
                int mid = (lo + hi) >> 1;
                if (batch[mid] < v) lo = mid + 1; else hi = mid;
            }
            return lo;
        };
        gcnt[g] = lb(g + 1) - lb(g);
        return;
    }
    __shared__ int c256[256];
    __shared__ int s[256];
    int t = threadIdx.x;
    c256[t] = 0;
    __syncthreads();
    int lo = bbase[blockIdx.x], n = btot[blockIdx.x];
    for (int e = lo + t; e < lo + n; e += 256) atomicAdd(&c256[dst_b[e] & 255], 1);
    __syncthreads();
    int cnt = c256[t];
    s[t] = cnt;
    __syncthreads();
    for (int d = 1; d < 256; d <<= 1) {
        int x = (t >= d) ? s[t - d] : 0;
        __syncthreads();
        s[t] += x;
        __syncthreads();
    }
    int node = blockIdx.x * 256 + t;
    if (node < N) {
        rowptr[node] = lo + (s[t] - cnt);          // bucket base + in-bucket exclusive scan
        dinv[node] = 1.0f / sqrtf((float)(cnt + 1));  // +1 self-loop
    }
}

// ---------------- bucket_fill: final CSR (col only), LDS ranks ----------------
__global__ __launch_bounds__(256) void bucket_fill_kernel(const int* __restrict__ src_b,
                                                          const int* __restrict__ dst_b,
                                                          const int* __restrict__ bbase,
                                                          const int* __restrict__ btot,
                                                          const int* __restrict__ rowptr,
                                                          int* __restrict__ col, int N) {
    __shared__ int f256[256];
    __shared__ int rp[256];
    int t = threadIdx.x;
    f256[t] = 0;
    int node = blockIdx.x * 256 + t;
    rp[t] = (node < N) ? rowptr[node] : 0;
    __syncthreads();
    int lo = bbase[blockIdx.x], n = btot[blockIdx.x];
    for (int e = lo + t; e < lo + n; e += 256) {
        int d = dst_b[e], sv = src_b[e];
        int li = d & 255;
        int slot = atomicAdd(&f256[li], 1);   // LDS atomic
        col[rp[li] + slot] = sv;
    }
}

// ---------------- scale m rows by dinv (prep for unweighted gather in agg0) ----------
__global__ __launch_bounds__(256) void scale_m_kernel(__half* __restrict__ m,
                                                      const float* __restrict__ dinv, int N) {
    int tot = N * 32;   // half2 elements
    __half2* m2 = (__half2*)m;
    for (int idx = blockIdx.x * 256 + threadIdx.x; idx < tot; idx += gridDim.x * 256) {
        float d = dinv[idx >> 5];
        float2 f = __half22float2(m2[idx]);
        f.x *= d;
        f.y *= d;
        m2[idx] = __float22half2_rn(f);
    }
}

// Predicated 32-wide gather over the CONTIGUOUS edge range of a node pair
// [r0, mid) -> A, [mid, r1) -> B. col reads are contiguous (merged s_load);
// invalid slots gather nodeA's own row (L1-hit, no extra L2 traffic).
// No serial tails: every pair completes in ceil(n/32) rounds, 32 loads in flight.
#define PAIR_GATHER(HBUF)                                                         \
    int n = r1 - r0;                                                              \
    for (int e = 0; e < n; e += 32) {                                             \
        int kA = mid - r0 - e;   /* #A-edges in this round */                     \
        int nr = n - e;          /* #valid edges this round */                    \
        int gi[32];                                                               \
        float v[32];                                                              \
        _Pragma("unroll")                                                         \
        for (int u = 0; u < 32; ++u) gi[u] = (u < nr) ? col[r0 + e + u] : nodeA;  \
        _Pragma("unroll")                                                         \
        for (int u = 0; u < 32; ++u)                                              \
            v[u] = __half2float(HBUF[(size_t)gi[u] * 64 + lane]);                 \
        _Pragma("unroll")                                                         \
        for (int u = 0; u < 32; ++u) {                                            \
            aA += (u < kA) ? v[u] : 0.0f;                                         \
            aB += (u >= kA && u < nr) ? v[u] : 0.0f;                              \
        }                                                                         \
    }

// ---------------- layer-0 aggregation (2 nodes/wave, m pre-scaled) ----------------
// h1 = relu(di * sum + b); output pre-scaled: s1 = di * h1
__global__ __launch_bounds__(256) void agg0_kernel(const __half* __restrict__ m,
                                                   const int* __restrict__ rowptr,
                                                   const int* __restrict__ col,
                                                   const float* __restrict__ dinv,
                                                   const float* __restrict__ bias,
                                                   __half* __restrict__ hout, int N, int E) {
    int wid = __builtin_amdgcn_readfirstlane((blockIdx.x * 256 + threadIdx.x) >> 6);
    int lane = threadIdx.x & 63;
    int nodeA = wid * 2;
    int nodeB = nodeA + 1;   // N even
    if (nodeA >= N) return;
    int r0 = rowptr[nodeA];
    int mid = rowptr[nodeB];
    int r1 = (nodeB + 1 < N) ? rowptr[nodeB + 1] : E;
    float diA = dinv[nodeA], diB = dinv[nodeB];
    float aA = __half2float(m[(size_t)nodeA * 64 + lane]);   // self term (pre-scaled)
    float aB = __half2float(m[(size_t)nodeB * 64 + lane]);
    PAIR_GATHER(m)
    float bv = bias[lane];
    float hA = fmaxf(diA * aA + bv, 0.0f);
    float hB = fmaxf(diB * aB + bv, 0.0f);
    hout[(size_t)nodeA * 64 + lane] = __float2half(diA * hA);
    hout[(size_t)nodeB * 64 + lane] = __float2half(diB * hB);
}

// ---------------- fused layer, 2 nodes/wave: h' = relu((A h) W + b) ----------------
// Input rows pre-scaled (s = dinv*h); gather unweighted; 4B edge records.
__global__ __launch_bounds__(256) void fused_kernel(const __half* __restrict__ h,
                                                    const int* __restrict__ rowptr,
                                                    const int* __restrict__ col,
                                                    const float* __restrict__ dinv,
                                                    const float* __restrict__ W,
                                                    const float* __restrict__ bias,
                                                    __half* __restrict__ hout, int N, int E,
                                                    int scaleOut) {
    __shared__ float Ws[64 * 64];
    {
        const float4* W4 = (const float4*)W;
        float4* Ws4 = (float4*)Ws;
        for (int i = threadIdx.x; i < 64 * 16; i += 256) Ws4[i] = W4[i];
    }

    int wid = __builtin_amdgcn_readfirstlane((blockIdx.x * 256 + threadIdx.x) >> 6);
    int lane = threadIdx.x & 63;
    int nodeA = wid * 2;
    int nodeB = nodeA + 1;   // N even
    bool act = (nodeA < N);
    float gA = 0.0f, gB = 0.0f;
    float diA = 0.0f, diB = 0.0f;

    if (act) {
        int r0 = rowptr[nodeA];
        int mid = rowptr[nodeB];
        int r1 = (nodeB + 1 < N) ? rowptr[nodeB + 1] : E;
        diA = dinv[nodeA];
        diB = dinv[nodeB];
        float aA = __half2float(h[(size_t)nodeA * 64 + lane]);   // self (pre-scaled)
        float aB = __half2float(h[(size_t)nodeB * 64 + lane]);
        PAIR_GATHER(h)
        gA = diA * aA;
        gB = diB * aB;
    }

    __syncthreads();   // W staging visible; all waves arrive

    if (act) {
        float bv = bias[lane];
        float accA = bv, accB = bv;
#pragma unroll
        for (int k = 0; k < 64; ++k) {
            float wv = Ws[k * 64 + lane];
            unsigned ga = __builtin_amdgcn_readlane(__float_as_uint(gA), k);
            unsigned gb = __builtin_amdgcn_readlane(__float_as_uint(gB), k);
            accA += __uint_as_float(ga) * wv;
            accB += __uint_as_float(gb) * wv;
        }
        accA = fmaxf(accA, 0.0f);
        accB = fmaxf(accB, 0.0f);
        if (scaleOut) { accA *= diA; accB *= diB; }   // pre-scale for next layer's gather
        hout[(size_t)nodeA * 64 + lane] = __float2half(accA);
        hout[(size_t)nodeB * 64 + lane] = __float2half(accB);
    }
}

// ---------------- pooling: segment sum over sorted batch ids ----------------
__global__ __launch_bounds__(256) void pool_kernel(const __half* __restrict__ h,
                                                   const int* __restrict__ batch,
                                                   float* __restrict__ gpool, int N) {
    const int NPW = 32;  // nodes per wave
    int wid = (blockIdx.x * 256 + threadIdx.x) >> 6;
    int lane = threadIdx.x & 63;
    int i0 = wid * NPW;
    if (i0 >= N) return;
    int i1 = min(i0 + NPW, N);
    int curg = batch[i0];
    float acc = 0.0f;
    for (int i = i0; i < i1; ++i) {
        int g = batch[i];
        if (g != curg) {
            atomicAdd(&gpool[curg * 64 + lane], acc);
            acc = 0.0f;
            curg = g;
        }
        acc += __half2float(h[(size_t)i * 64 + lane]);
    }
    atomicAdd(&gpool[curg * 64 + lane], acc);
}

// ---------------- final: out = (gpool/count) @ Wlin + blin ----------------
__global__ void final_kernel(const float* __restrict__ gpool, const int* __restrict__ gcnt,
                             const float* __restrict__ Wlin, const float* __restrict__ blin,
                             float* __restrict__ out) {
    int t = threadIdx.x;
    if (t >= NGRAPH * COUT) return;
    int g = t / COUT, o = t - g * COUT;
    float c = (float)gcnt[g];
    if (c < 1.0f) c = 1.0f;
    float s = 0.0f;
    for (int k = 0; k < 64; ++k) s += gpool[g * 64 + k] * Wlin[k * COUT + o];
    out[t] = s / c + blin[o];
}

extern "C" void kernel_launch(void* const* d_in, const int* in_sizes, int n_in,
                              void* d_out, int out_size, void* d_ws, size_t ws_size,
                              hipStream_t stream) {
    const float* x    = (const float*)d_in[0];
    const int*   ei   = (const int*)d_in[1];
    const int*   batch= (const int*)d_in[2];
    const float* W0   = (const float*)d_in[3];
    const float* b0   = (const float*)d_in[4];
    const float* Ws   = (const float*)d_in[5];
    const float* bs   = (const float*)d_in[6];
    const float* Wlin = (const float*)d_in[7];
    const float* blin = (const float*)d_in[8];
    float* out = (float*)d_out;

    const int N = NNODES, E = NEDGES;
    const int* srcp = ei;          // edge_index[0]
    const int* dstp = ei + E;      // edge_index[1]

    char* w = (char*)d_ws;
    float* gpool  = (float*)w; w += (size_t)NGRAPH * 64 * 4;
    size_t zero_bytes = (size_t)(w - (char*)d_ws);   // only gpool needs zeroing
    int*   gcnt   = (int*)w;   w += (size_t)NGRAPH * 4;
    float* dinv   = (float*)w; w += (size_t)N * 4;
    int*   rowptr = (int*)w;   w += (size_t)N * 4;
    int*   hist   = (int*)w;   w += (size_t)NB * NC * 4;
    int*   btot   = (int*)w;   w += (size_t)NB * 4;
    int*   bbase  = (int*)w;   w += (size_t)NB * 4;
    int*   src_b  = (int*)w;   w += (size_t)E * 4;
    int*   dst_b  = (int*)w;   w += (size_t)E * 4;
    int*   col    = (int*)w;   w += (size_t)E * 4;
    __half* bufA  = (__half*)w; w += (size_t)N * 64 * 2;   // also guards col OOB-prefetch
    __half* bufB  = (__half*)w; w += (size_t)N * 64 * 2;

    hipMemsetAsync(d_ws, 0, zero_bytes, stream);

    int gemmblocks = (N + 31) / 32;       // 3125: 8 rows/wave, 4 waves/block

    // P1 histogram + layer-0 GEMM co-scheduled (independent)
    hist_gemm_kernel<128><<<NC + gemmblocks, 256, 0, stream>>>(
        dstp, hist, E, x, W0, bufB, N, NC);
    scan_chunks_kernel<<<NB, 256, 0, stream>>>(hist, btot);
    scan_buckets_kernel<<<1, 512, 0, stream>>>(btot, bbase);
    scatter_kernel<<<NC, 256, 0, stream>>>(srcp, dstp, hist, bbase, src_b, dst_b, E);
    bucket_prep_kernel<<<NB + 1, 256, 0, stream>>>(dst_b, bbase, btot, rowptr, dinv,
                                                   batch, gcnt, N);
    bucket_fill_kernel<<<NB, 256, 0, stream>>>(src_b, dst_b, bbase, btot, rowptr, col, N);
    scale_m_kernel<<<2048, 256, 0, stream>>>(bufB, dinv, N);

    int pairblocks = (N / 2 + 3) / 4;     // 2 nodes/wave, 4 waves/block

    agg0_kernel<<<pairblocks, 256, 0, stream>>>(bufB, rowptr, col, dinv, b0, bufA, N, E);

    // layers 1..9 fused: h' = relu((A h) W + b); rows pre-scaled except the last
    __half* hin = bufA;
    __half* hout = bufB;
    for (int l = 0; l < NSTACK; ++l) {
        int scaleOut = (l < NSTACK - 1) ? 1 : 0;
        fused_kernel<<<pairblocks, 256, 0, stream>>>(hin, rowptr, col, dinv,
                                                     Ws + (size_t)l * 64 * 64,
                                                     bs + (size_t)l * 64, hout, N, E,
                                                     scaleOut);
        __half* t = hin; hin = hout; hout = t;
    }
    // final h is in `hin` after the swap

    int pwaves = (N + 31) / 32;
    int pblocks = (pwaves + 3) / 4;
    pool_kernel<<<pblocks, 256, 0, stream>>>(hin, batch, gpool, N);
    final_kernel<<<1, 896, 0, stream>>>(gpool, gcnt, Wlin, blin, out);
}

// Round 14
// 685.649 us; speedup vs baseline: 2.0634x; 1.4577x over previous
//
#include <hip/hip_runtime.h>
#include <hip/hip_fp16.h>

#define NNODES 100000
#define NEDGES 1600000
#define NGRAPH 128
#define CIN 128
#define CH 64
#define COUT 7
#define NSTACK 9

#define NB 391      // buckets of 256 nodes: ceil(100000/256)
#define CHUNK 2048  // edges per histogram/scatter block
#define NC 782      // ceil(1600000/2048)

// ---------------- merged: P1 bucket histogram (LDS only) + layer-0 GEMM ----------------
template <int K>
__global__ __launch_bounds__(256) void hist_gemm_kernel(const int* __restrict__ dst,
                                                        int* __restrict__ hist, int E,
                                                        const float* __restrict__ h,
                                                        const float* __restrict__ W,
                                                        __half* __restrict__ m, int N,
                                                        int histBlocks) {
    __shared__ float Ws[K * 64];
    __shared__ int lh[NB];
    if (blockIdx.x < (unsigned)histBlocks) {
        for (int i = threadIdx.x; i < NB; i += 256) lh[i] = 0;
        __syncthreads();
        int e0 = blockIdx.x * CHUNK;
        int e1 = min(e0 + CHUNK, E);
        for (int e = e0 + threadIdx.x; e < e1; e += 256)
            atomicAdd(&lh[dst[e] >> 8], 1);   // LDS atomic
        __syncthreads();
        for (int i = threadIdx.x; i < NB; i += 256) hist[i * NC + (int)blockIdx.x] = lh[i];
        return;
    }
    // ---- GEMM part: 8 rows/wave ----
    int gb = blockIdx.x - histBlocks;
    for (int i = threadIdx.x; i < K * 64; i += 256) Ws[i] = W[i];
    __syncthreads();
    const int ROWS = 8;
    int wid = (gb * 256 + (int)threadIdx.x) >> 6;
    int lane = threadIdx.x & 63;
    long row0 = (long)wid * ROWS;
    if (row0 >= N) return;
    const float* hr = h + row0 * K + lane;

    float hv[ROWS][K / 64];
#pragma unroll
    for (int r = 0; r < ROWS; ++r)
#pragma unroll
        for (int q = 0; q < K / 64; ++q)
            hv[r][q] = hr[(size_t)r * K + q * 64];

    float acc[ROWS];
#pragma unroll
    for (int r = 0; r < ROWS; ++r) acc[r] = 0.0f;

#pragma unroll
    for (int k = 0; k < K; ++k) {
        float wv = Ws[k * 64 + lane];
#pragma unroll
        for (int r = 0; r < ROWS; ++r) {
            unsigned hb = __builtin_amdgcn_readlane(__float_as_uint(hv[r][k >> 6]), k & 63);
            acc[r] += __uint_as_float(hb) * wv;
        }
    }

    __half* mo = m + row0 * 64 + lane;
#pragma unroll
    for (int r = 0; r < ROWS; ++r) mo[r * 64] = __float2half(acc[r]);
}

// ---------------- P2a: exclusive scan of each bucket row over NC chunks ----------------
__global__ __launch_bounds__(256) void scan_chunks_kernel(int* __restrict__ hist,
                                                          int* __restrict__ btot) {
    int b = blockIdx.x;
    int t = threadIdx.x;
    int* row = hist + b * NC;
    int v[4];
    int base = 4 * t;   // 4 elements/thread covers 1024 >= NC
#pragma unroll
    for (int u = 0; u < 4; ++u) v[u] = (base + u < NC) ? row[base + u] : 0;
    int tsum = v[0] + v[1] + v[2] + v[3];
    __shared__ int s[256];
    s[t] = tsum;
    __syncthreads();
    for (int d = 1; d < 256; d <<= 1) {
        int x = (t >= d) ? s[t - d] : 0;
        __syncthreads();
        s[t] += x;
        __syncthreads();
    }
    int run = s[t] - tsum;   // exclusive prefix of thread sums
    if (t == 255) btot[b] = s[255];
#pragma unroll
    for (int u = 0; u < 4; ++u) {
        if (base + u < NC) row[base + u] = run;
        run += v[u];
    }
}

// ---- exclusive scan of NB totals -> bases; also writes grand total at out[NB] ----
__global__ void scan_buckets_kernel(const int* __restrict__ tot, int* __restrict__ out) {
    __shared__ int s[512];
    int t = threadIdx.x;
    int v = (t < NB) ? tot[t] : 0;
    s[t] = v;
    __syncthreads();
    for (int d = 1; d < 512; d <<= 1) {
        int x = (t >= d) ? s[t - d] : 0;
        __syncthreads();
        s[t] += x;
        __syncthreads();
    }
    if (t < NB) out[t] = s[t] - v;
    if (t == NB - 1) out[NB] = s[t];   // grand total
}

// ---------------- P3: scatter edges into dst buckets (LDS ranks, no global atomics) ----
__global__ __launch_bounds__(256) void scatter_kernel(const int* __restrict__ src,
                                                      const int* __restrict__ dst,
                                                      const int* __restrict__ hist,
                                                      const int* __restrict__ bbase,
                                                      int* __restrict__ src_b,
                                                      int* __restrict__ dst_b, int E) {
    __shared__ int offs[NB];
    for (int b = threadIdx.x; b < NB; b += 256)
        offs[b] = hist[b * NC + (int)blockIdx.x] + bbase[b];
    __syncthreads();
    int e0 = blockIdx.x * CHUNK;
    int e1 = min(e0 + CHUNK, E);
    for (int e = e0 + threadIdx.x; e < e1; e += 256) {
        int d = dst[e], s = src[e];
        int pos = atomicAdd(&offs[d >> 8], 1);   // LDS atomic
        src_b[pos] = s;
        dst_b[pos] = d;
    }
}

// ---- bucket_prep: degree count + PADDED in-bucket rowptr offsets + dinv (+gcnt) ----
// Each node's degree padded to a multiple of 8 (pad slots -> zero row N), so
// every rowptr is 8-aligned and gathers need no tails/predication.
__global__ __launch_bounds__(256) void bucket_prep_kernel(const int* __restrict__ dst_b,
                                                          const int* __restrict__ bbase,
                                                          const int* __restrict__ btot,
                                                          int* __restrict__ rowptr,
                                                          int* __restrict__ pbt,
                                                          float* __restrict__ dinv,
                                                          const int* __restrict__ batch,
                                                          int* __restrict__ gcnt, int N) {
    if ((int)blockIdx.x == NB) {   // per-graph node counts via binary search
        int g = threadIdx.x;
        if (g >= NGRAPH) return;
        auto lb = [&](int v) {
            int lo = 0, hi = N;
            while (lo < hi) {
                int mid = (lo + hi) >> 1;
                if (batch[mid] < v) lo = mid + 1; else hi = mid;
            }
            return lo;
        };
        gcnt[g] = lb(g + 1) - lb(g);
        return;
    }
    __shared__ int c256[256];
    __shared__ int s[256];
    int t = threadIdx.x;
    c256[t] = 0;
    __syncthreads();
    int lo = bbase[blockIdx.x], n = btot[blockIdx.x];
    for (int e = lo + t; e < lo + n; e += 256) atomicAdd(&c256[dst_b[e] & 255], 1);
    __syncthreads();
    int cnt = c256[t];
    int pcnt = (cnt + 7) & ~7;   // pad to multiple of 8
    s[t] = pcnt;
    __syncthreads();
    for (int d = 1; d < 256; d <<= 1) {
        int x = (t >= d) ? s[t - d] : 0;
        __syncthreads();
        s[t] += x;
        __syncthreads();
    }
    int node = blockIdx.x * 256 + t;
    if (node < N) {
        rowptr[node] = s[t] - pcnt;                   // in-bucket padded offset (abs later)
        dinv[node] = 1.0f / sqrtf((float)(cnt + 1));  // +1 self-loop (real degree)
    }
    if (t == 255) pbt[blockIdx.x] = s[255];           // padded bucket total
}

// ---- rowptr fixup: add padded bucket base; set rowptr[N] = grand total ----
__global__ void rowptr_fix_kernel(int* __restrict__ rowptr, const int* __restrict__ pbbase,
                                  int N) {
    int i = blockIdx.x * 256 + threadIdx.x;
    if (i < N) rowptr[i] += pbbase[i >> 8];
    if (i == 0) rowptr[N] = pbbase[NB];
}

// ---------------- bucket_fill: padded CSR (col only), LDS ranks; pad -> N ----------------
__global__ __launch_bounds__(256) void bucket_fill_kernel(const int* __restrict__ src_b,
                                                          const int* __restrict__ dst_b,
                                                          const int* __restrict__ bbase,
                                                          const int* __restrict__ btot,
                                                          const int* __restrict__ rowptr,
                                                          int* __restrict__ col, int N) {
    __shared__ int f256[256];
    __shared__ int rp[256];
    int t = threadIdx.x;
    f256[t] = 0;
    int node = blockIdx.x * 256 + t;
    rp[t] = (node < N) ? rowptr[node] : 0;
    __syncthreads();
    int lo = bbase[blockIdx.x], n = btot[blockIdx.x];
    for (int e = lo + t; e < lo + n; e += 256) {
        int d = dst_b[e], sv = src_b[e];
        int li = d & 255;
        int slot = atomicAdd(&f256[li], 1);   // LDS atomic
        col[rp[li] + slot] = sv;
    }
    __syncthreads();
    if (node < N) {   // fill padding with zero-row index N
        int c = f256[t];
        int pc = (c + 7) & ~7;
        int base = rp[t];
        for (int p = c; p < pc; ++p) col[base + p] = N;
    }
}

// ---------------- scale m rows by dinv + zero the pad row N ----------------
__global__ __launch_bounds__(256) void scale_m_kernel(__half* __restrict__ m,
                                                      __half* __restrict__ other,
                                                      const float* __restrict__ dinv, int N) {
    if (blockIdx.x == 0 && threadIdx.x < 64) {   // zero row N of both layer buffers
        m[(size_t)N * 64 + threadIdx.x] = __float2half(0.0f);
        other[(size_t)N * 64 + threadIdx.x] = __float2half(0.0f);
    }
    int tot = N * 32;   // half2 elements
    __half2* m2 = (__half2*)m;
    for (int idx = blockIdx.x * 256 + threadIdx.x; idx < tot; idx += gridDim.x * 256) {
        float d = dinv[idx >> 5];
        float2 f = __half22float2(m2[idx]);
        f.x *= d;
        f.y *= d;
        m2[idx] = __float22half2_rn(f);
    }
}

// Pair gather over contiguous padded ranges [r0,mid)->A, [mid,r1)->B.
// r0, mid, r1 all multiples of 8 -> 8-blocks never straddle the split; the
// A/B choice per block is wave-uniform (SGPR compare). col indices are scalar
// (s_load) -> gathers use SGPR base addressing, ~zero VALU per load.
__device__ __forceinline__ void pair_gather(const __half* __restrict__ h,
                                            const int* __restrict__ col,
                                            int r0, int mid, int r1, int lane,
                                            float& aA, float& aB) {
    int n = r1 - r0;
    int e = 0;
    for (; e + 16 <= n; e += 16) {
        int base = r0 + e;
        int c[16];
        float v[16];
#pragma unroll
        for (int u = 0; u < 16; ++u) c[u] = col[base + u];
#pragma unroll
        for (int u = 0; u < 16; ++u) v[u] = __half2float(h[(size_t)c[u] * 64 + lane]);
        float s0 = ((v[0] + v[1]) + (v[2] + v[3])) + ((v[4] + v[5]) + (v[6] + v[7]));
        float s1 = ((v[8] + v[9]) + (v[10] + v[11])) + ((v[12] + v[13]) + (v[14] + v[15]));
        bool b0 = (base < mid);       // uniform per 8-block
        bool b1 = (base + 8 < mid);
        aA += b0 ? s0 : 0.0f;
        aB += b0 ? 0.0f : s0;
        aA += b1 ? s1 : 0.0f;
        aB += b1 ? 0.0f : s1;
    }
    if (e + 8 <= n) {   // remainder is exactly 0 or 8
        int base = r0 + e;
        int c[8];
        float v[8];
#pragma unroll
        for (int u = 0; u < 8; ++u) c[u] = col[base + u];
#pragma unroll
        for (int u = 0; u < 8; ++u) v[u] = __half2float(h[(size_t)c[u] * 64 + lane]);
        float s0 = ((v[0] + v[1]) + (v[2] + v[3])) + ((v[4] + v[5]) + (v[6] + v[7]));
        bool b0 = (base < mid);
        aA += b0 ? s0 : 0.0f;
        aB += b0 ? 0.0f : s0;
    }
}

// ---------------- layer-0 aggregation (2 nodes/wave, m pre-scaled) ----------------
__global__ __launch_bounds__(256) void agg0_kernel(const __half* __restrict__ m,
                                                   const int* __restrict__ rowptr,
                                                   const int* __restrict__ col,
                                                   const float* __restrict__ dinv,
                                                   const float* __restrict__ bias,
                                                   __half* __restrict__ hout, int N) {
    int wid = __builtin_amdgcn_readfirstlane((blockIdx.x * 256 + threadIdx.x) >> 6);
    int lane = threadIdx.x & 63;
    int nodeA = wid * 2;
    int nodeB = nodeA + 1;   // N even
    if (nodeA >= N) return;
    int r0 = rowptr[nodeA];
    int mid = rowptr[nodeB];
    int r1 = rowptr[nodeB + 1];
    float diA = dinv[nodeA], diB = dinv[nodeB];
    float aA = __half2float(m[(size_t)nodeA * 64 + lane]);   // self (pre-scaled)
    float aB = __half2float(m[(size_t)nodeB * 64 + lane]);
    pair_gather(m, col, r0, mid, r1, lane, aA, aB);
    float bv = bias[lane];
    float hA = fmaxf(diA * aA + bv, 0.0f);
    float hB = fmaxf(diB * aB + bv, 0.0f);
    hout[(size_t)nodeA * 64 + lane] = __float2half(diA * hA);   // pre-scaled out
    hout[(size_t)nodeB * 64 + lane] = __float2half(diB * hB);
}

// ---------------- fused layer, 2 nodes/wave: h' = relu((A h) W + b) ----------------
__global__ __launch_bounds__(256) void fused_kernel(const __half* __restrict__ h,
                                                    const int* __restrict__ rowptr,
                                                    const int* __restrict__ col,
                                                    const float* __restrict__ dinv,
                                                    const float* __restrict__ W,
                                                    const float* __restrict__ bias,
                                                    __half* __restrict__ hout, int N,
                                                    int scaleOut) {
    __shared__ float Ws[64 * 64];
    {
        const float4* W4 = (const float4*)W;
        float4* Ws4 = (float4*)Ws;
        for (int i = threadIdx.x; i < 64 * 16; i += 256) Ws4[i] = W4[i];
    }

    int wid = __builtin_amdgcn_readfirstlane((blockIdx.x * 256 + threadIdx.x) >> 6);
    int lane = threadIdx.x & 63;
    int nodeA = wid * 2;
    int nodeB = nodeA + 1;   // N even
    bool act = (nodeA < N);
    float gA = 0.0f, gB = 0.0f;
    float diA = 0.0f, diB = 0.0f;

    if (act) {
        int r0 = rowptr[nodeA];
        int mid = rowptr[nodeB];
        int r1 = rowptr[nodeB + 1];
        diA = dinv[nodeA];
        diB = dinv[nodeB];
        float aA = __half2float(h[(size_t)nodeA * 64 + lane]);   // self (pre-scaled)
        float aB = __half2float(h[(size_t)nodeB * 64 + lane]);
        pair_gather(h, col, r0, mid, r1, lane, aA, aB);
        gA = diA * aA;
        gB = diB * aB;
    }

    __syncthreads();   // W staging visible; all waves arrive

    if (act) {
        float bv = bias[lane];
        float accA = bv, accB = bv;
#pragma unroll
        for (int k = 0; k < 64; ++k) {
            float wv = Ws[k * 64 + lane];
            unsigned ga = __builtin_amdgcn_readlane(__float_as_uint(gA), k);
            unsigned gb = __builtin_amdgcn_readlane(__float_as_uint(gB), k);
            accA += __uint_as_float(ga) * wv;
            accB += __uint_as_float(gb) * wv;
        }
        accA = fmaxf(accA, 0.0f);
        accB = fmaxf(accB, 0.0f);
        if (scaleOut) { accA *= diA; accB *= diB; }   // pre-scale for next layer
        hout[(size_t)nodeA * 64 + lane] = __float2half(accA);
        hout[(size_t)nodeB * 64 + lane] = __float2half(accB);
    }
}

// ---------------- pooling: segment sum over sorted batch ids ----------------
__global__ __launch_bounds__(256) void pool_kernel(const __half* __restrict__ h,
                                                   const int* __restrict__ batch,
                                                   float* __restrict__ gpool, int N) {
    const int NPW = 32;  // nodes per wave
    int wid = (blockIdx.x * 256 + threadIdx.x) >> 6;
    int lane = threadIdx.x & 63;
    int i0 = wid * NPW;
    if (i0 >= N) return;
    int i1 = min(i0 + NPW, N);
    int curg = batch[i0];
    float acc = 0.0f;
    for (int i = i0; i < i1; ++i) {
        int g = batch[i];
        if (g != curg) {
            atomicAdd(&gpool[curg * 64 + lane], acc);
            acc = 0.0f;
            curg = g;
        }
        acc += __half2float(h[(size_t)i * 64 + lane]);
    }
    atomicAdd(&gpool[curg * 64 + lane], acc);
}

// ---------------- final: out = (gpool/count) @ Wlin + blin ----------------
__global__ void final_kernel(const float* __restrict__ gpool, const int* __restrict__ gcnt,
                             const float* __restrict__ Wlin, const float* __restrict__ blin,
                             float* __restrict__ out) {
    int t = threadIdx.x;
    if (t >= NGRAPH * COUT) return;
    int g = t / COUT, o = t - g * COUT;
    float c = (float)gcnt[g];
    if (c < 1.0f) c = 1.0f;
    float s = 0.0f;
    for (int k = 0; k < 64; ++k) s += gpool[g * 64 + k] * Wlin[k * COUT + o];
    out[t] = s / c + blin[o];
}

extern "C" void kernel_launch(void* const* d_in, const int* in_sizes, int n_in,
                              void* d_out, int out_size, void* d_ws, size_t ws_size,
                              hipStream_t stream) {
    const float* x    = (const float*)d_in[0];
    const int*   ei   = (const int*)d_in[1];
    const int*   batch= (const int*)d_in[2];
    const float* W0   = (const float*)d_in[3];
    const float* b0   = (const float*)d_in[4];
    const float* Ws   = (const float*)d_in[5];
    const float* bs   = (const float*)d_in[6];
    const float* Wlin = (const float*)d_in[7];
    const float* blin = (const float*)d_in[8];
    float* out = (float*)d_out;

    const int N = NNODES, E = NEDGES;
    const int* srcp = ei;          // edge_index[0]
    const int* dstp = ei + E;      // edge_index[1]

    char* w = (char*)d_ws;
    float* gpool  = (float*)w; w += (size_t)NGRAPH * 64 * 4;
    size_t zero_bytes = (size_t)(w - (char*)d_ws);   // only gpool needs zeroing
    int*   gcnt   = (int*)w;   w += (size_t)NGRAPH * 4;
    float* dinv   = (float*)w; w += (size_t)N * 4;
    int*   rowptr = (int*)w;   w += (size_t)(N + 1) * 4;
    int*   hist   = (int*)w;   w += (size_t)NB * NC * 4;
    int*   btot   = (int*)w;   w += (size_t)NB * 4;
    int*   bbase  = (int*)w;   w += (size_t)(NB + 1) * 4;
    int*   pbt    = (int*)w;   w += (size_t)NB * 4;
    int*   pbbase = (int*)w;   w += (size_t)(NB + 1) * 4;
    int*   src_b  = (int*)w;   w += (size_t)E * 4;
    int*   dst_b  = (int*)w;   w += (size_t)E * 4;
    int*   col    = (int*)w;   w += ((size_t)E + 8 * N) * 4;   // padded CSR
    __half* bufA  = (__half*)w; w += (size_t)(N + 1) * 64 * 2;  // +zero row N
    __half* bufB  = (__half*)w; w += (size_t)(N + 1) * 64 * 2;

    hipMemsetAsync(d_ws, 0, zero_bytes, stream);

    int nblocks = (N + 255) / 256;       // 391
    int gemmblocks = (N + 31) / 32;      // 3125: 8 rows/wave, 4 waves/block

    // P1 histogram + layer-0 GEMM co-scheduled (independent)
    hist_gemm_kernel<128><<<NC + gemmblocks, 256, 0, stream>>>(
        dstp, hist, E, x, W0, bufB, N, NC);
    scan_chunks_kernel<<<NB, 256, 0, stream>>>(hist, btot);
    scan_buckets_kernel<<<1, 512, 0, stream>>>(btot, bbase);
    scatter_kernel<<<NC, 256, 0, stream>>>(srcp, dstp, hist, bbase, src_b, dst_b, E);
    bucket_prep_kernel<<<NB + 1, 256, 0, stream>>>(dst_b, bbase, btot, rowptr, pbt, dinv,
                                                   batch, gcnt, N);
    scan_buckets_kernel<<<1, 512, 0, stream>>>(pbt, pbbase);
    rowptr_fix_kernel<<<nblocks, 256, 0, stream>>>(rowptr, pbbase, N);
    bucket_fill_kernel<<<NB, 256, 0, stream>>>(src_b, dst_b, bbase, btot, rowptr, col, N);
    scale_m_kernel<<<2048, 256, 0, stream>>>(bufB, bufA, dinv, N);

    int pairblocks = (N / 2 + 3) / 4;     // 2 nodes/wave, 4 waves/block

    agg0_kernel<<<pairblocks, 256, 0, stream>>>(bufB, rowptr, col, dinv, b0, bufA, N);

    // layers 1..9 fused: h' = relu((A h) W + b); rows pre-scaled except the last
    __half* hin = bufA;
    __half* hout = bufB;
    for (int l = 0; l < NSTACK; ++l) {
        int scaleOut = (l < NSTACK - 1) ? 1 : 0;
        fused_kernel<<<pairblocks, 256, 0, stream>>>(hin, rowptr, col, dinv,
                                                     Ws + (size_t)l * 64 * 64,
                                                     bs + (size_t)l * 64, hout, N,
                                                     scaleOut);
        __half* t = hin; hin = hout; hout = t;
    }
    // final h is in `hin` after the swap

    int pwaves = (N + 31) / 32;
    int pblocks = (pwaves + 3) / 4;
    pool_kernel<<<pblocks, 256, 0, stream>>>(hin, batch, gpool, N);
    final_kernel<<<1, 896, 0, stream>>>(gpool, gcnt, Wlin, blin, out);
}